// Round 1
// baseline (27566.785 us; speedup 1.0000x reference)
//
#include <hip/hip_runtime.h>

typedef _Float16 f16;
typedef _Float16 h2_t __attribute__((ext_vector_type(2)));
typedef _Float16 h8_t __attribute__((ext_vector_type(8)));
typedef float    f4_t __attribute__((ext_vector_type(4)));

__device__ __forceinline__ float fdot2u(unsigned int a, unsigned int b, float c) {
  return __builtin_amdgcn_fdot2(__builtin_bit_cast(h2_t, a),
                                __builtin_bit_cast(h2_t, b), c, false);
}

// ============ generic f16-input MFMA GEMM: C[z] = A[z] @ B (+bias)(+accum)(+relu) ============
// A: (M x K) f16 row-major (row stride lda, batch stride sAz)
// B: (K x N) f16 row-major (row stride ldb)
// C: f32 or f16, row stride ldc, batch stride sCz
// Uses consistent (lane,i)->k convention for A and B fragments (k-permutation invariant).
// C/D layout: col = lane&15, row = (lane>>4)*4 + reg   [m89-verified]
template<int F16OUT, int ACCUM, int RELU, int BIASF>
__global__ __launch_bounds__(256) void gemm16(
    const f16* __restrict__ Ap, long lda, long sAz,
    const f16* __restrict__ Bp, long ldb,
    void* __restrict__ Cp, long ldc, long sCz,
    const float* __restrict__ biasN,
    int M, int N, int K)
{
  const int lane = threadIdx.x & 63;
  const int wv   = threadIdx.x >> 6;          // wave 0..3 -> 16-row stripe
  const int rl = lane & 15, kb = lane >> 4;
  const long z = blockIdx.z;
  const f16* Az = Ap + z * sAz;
  const int rowA = blockIdx.x * 64 + wv * 16 + rl;
  const long rA = (rowA < M) ? rowA : 0;
  const int colBase = blockIdx.y * 64;
  f4_t acc[4];
  #pragma unroll
  for (int c = 0; c < 4; ++c) acc[c] = 0.0f;

  for (int k0 = 0; k0 < K; k0 += 32) {
    h8_t af = *(const h8_t*)(Az + rA * lda + (k0 + kb * 8));
    h8_t bf[4];
    #pragma unroll
    for (int i = 0; i < 8; ++i) {
      long krow = (long)(k0 + kb * 8 + i) * ldb + colBase + rl;
      #pragma unroll
      for (int c = 0; c < 4; ++c) bf[c][i] = Bp[krow + 16 * c];
    }
    #pragma unroll
    for (int c = 0; c < 4; ++c)
      acc[c] = __builtin_amdgcn_mfma_f32_16x16x32_f16(af, bf[c], acc[c], 0, 0, 0);
  }

  #pragma unroll
  for (int c = 0; c < 4; ++c) {
    const int col = colBase + c * 16 + rl;
    #pragma unroll
    for (int g = 0; g < 4; ++g) {
      const int row = blockIdx.x * 64 + wv * 16 + kb * 4 + g;
      if (row < M) {
        float v = acc[c][g];
        const long ci = z * sCz + (long)row * ldc + col;
        if (BIASF) v += biasN[col];
        if (ACCUM) v += F16OUT ? (float)((const f16*)Cp)[ci] : ((const float*)Cp)[ci];
        if (RELU) v = fmaxf(v, 0.0f);
        if (F16OUT) ((f16*)Cp)[ci] = (f16)v;
        else        ((float*)Cp)[ci] = v;
      }
    }
  }
}

// ============ small helper kernels ============
__global__ void k_cvt(const float* __restrict__ s, f16* __restrict__ d, int n) {
  int i = blockIdx.x * 256 + threadIdx.x;
  if (i < n) d[i] = (f16)s[i];
}

__global__ void k_build_cv(const float* __restrict__ C2, const float* __restrict__ mul,
                           f16* __restrict__ cv) {
  int i = blockIdx.x * 256 + threadIdx.x;   // 512*512
  int r = i >> 9;
  cv[i] = (f16)(C2[i] / mul[r]);
}

// DvT (64x512): DvT[k][n] = Dtild[n][k]/mul[n]
__global__ void k_build_dvt(const float* __restrict__ Dt, const float* __restrict__ mul,
                            f16* __restrict__ dvt) {
  int i = blockIdx.x * 256 + threadIdx.x;   // 64*512
  int k = i >> 9, n = i & 511;
  dvt[i] = (f16)(Dt[n * 64 + k] / mul[n]);
}

// d = f16(2I - s), 512x512
__global__ void k_2im(const float* __restrict__ s, f16* __restrict__ d) {
  int i = blockIdx.x * 256 + threadIdx.x;
  int r = i >> 9, c = i & 511;
  d[i] = (f16)(((r == c) ? 2.0f : 0.0f) - s[i]);
}

// out (C x R) = transpose of in (R x C), f16
__global__ void k_tr16(const f16* __restrict__ s, f16* __restrict__ d, int R, int C) {
  int i = blockIdx.x * 256 + threadIdx.x;
  if (i < R * C) { int j = i / R, r = i % R; d[i] = s[r * C + j]; }
}

// WoutT (1088 x 64): rows 0..511 = C1^T, 512..1023 = D11^T, 1024..1087 = D12^T
__global__ void k_woutt(const float* __restrict__ C1, const float* __restrict__ D11,
                        const float* __restrict__ D12, f16* __restrict__ Wo) {
  int i = blockIdx.x * 256 + threadIdx.x;   // 1088*64
  int k = i >> 6, j = i & 63;
  float v = (k < 512) ? C1[j * 512 + k]
          : (k < 1024) ? D11[j * 512 + (k - 512)]
                       : D12[j * 64 + (k - 1024)];
  Wo[i] = (f16)v;
}

// cb = Einv @ F_b
__global__ void k_cb(const f16* __restrict__ X, const float* __restrict__ Fb,
                     float* __restrict__ cb) {
  int i = threadIdx.x;   // 512 threads, 1 block
  float a = 0.0f;
  for (int k = 0; k < 512; ++k) a += (float)X[i * 512 + k] * Fb[k];
  cb[i] = a;
}

// bias0[0:512]=cb ; bias0[512+j]=Cv@cb + bv
__global__ void k_bias0(const f16* __restrict__ Cv, const float* __restrict__ cb,
                        const float* __restrict__ bv, float* __restrict__ b0) {
  int i = blockIdx.x * 512 + threadIdx.x;   // 1024 total
  if (i < 512) b0[i] = cb[i];
  else {
    int j = i - 512;
    float a = bv[j];
    for (int k = 0; k < 512; ++k) a += (float)Cv[j * 512 + k] * cb[k];
    b0[i] = a;
  }
}

// u (B,NU,T) f32 -> Upack [t][b][nu] f16 (LDS-tiled transpose)
__global__ void k_packu(const float* __restrict__ u, f16* __restrict__ up) {
  __shared__ f16 tile[64][65];
  int b = blockIdx.y, t0 = blockIdx.x << 6;
  int tid = threadIdx.x;
  #pragma unroll
  for (int it = 0; it < 16; ++it) {
    int idx = it * 256 + tid; int i = idx >> 6, tt = idx & 63;
    tile[tt][i] = (f16)u[((long)b * 64 + i) * 1024 + t0 + tt];
  }
  __syncthreads();
  #pragma unroll
  for (int it = 0; it < 16; ++it) {
    int idx = it * 256 + tid; int tt = idx >> 6, i = idx & 63;
    up[((long)(t0 + tt) * 32 + b) * 64 + i] = tile[tt][i];
  }
}

// Pack Wbig = [[A1 A2],[M1 M2]] (1024x1024 f16) into per-thread register layout.
// uint U = ((s*32+jj)*512 + tid)*4 + p ; thread (tid: q=tid&3,r=tid>>2) of slice s
// holds half2 pairs for row R=128s+r, k = 256q + 8jj + 2p
__global__ void k_packw(const f16* __restrict__ A1, const f16* __restrict__ A2,
                        const f16* __restrict__ M1, const f16* __restrict__ M2,
                        unsigned int* __restrict__ Wp) {
  int U = blockIdx.x * 256 + threadIdx.x;   // 524288
  int p = U & 3; int V = U >> 2;
  int tid = V & 511; int sj = V >> 9;
  int jj = sj & 31; int s = sj >> 5;
  int q = tid & 3, r = tid >> 2;
  int R = s * 128 + r;
  int k = q * 256 + jj * 8 + p * 2;
  f16 g0, g1;
  if (R < 512) {
    if (k < 512) { g0 = A1[R * 512 + k];         g1 = A1[R * 512 + k + 1]; }
    else         { g0 = A2[R * 512 + k - 512];   g1 = A2[R * 512 + k - 511]; }
  } else {
    int Rm = R - 512;
    if (k < 512) { g0 = M1[Rm * 512 + k];        g1 = M1[Rm * 512 + k + 1]; }
    else         { g0 = M2[Rm * 512 + k - 512];  g1 = M2[Rm * 512 + k - 511]; }
  }
  unsigned int lo = __builtin_bit_cast(unsigned short, g0);
  unsigned int hi = __builtin_bit_cast(unsigned short, g1);
  Wp[U] = lo | (hi << 16);
}

// ============ the sequential scan: persistent, 256 WGs = 32 batches x 8 slices ============
// block i -> slice s=i>>5, batch b=i&31  (i%8 == b%8 -> a batch's 8 WGs share an XCD; heuristic only)
// state row Sst[t][b][0:1024] f16 ; per-step: one agent-scope all-to-all within batch + counter sync
__global__ __launch_bounds__(512, 2) void k_scan(
    const uint4* __restrict__ Wp4,
    const f16* __restrict__ bHV,
    const float* __restrict__ b0,
    f16* __restrict__ Sst,
    unsigned int* __restrict__ cnt)
{
  const int wg = blockIdx.x;
  const int s = wg >> 5, b = wg & 31;
  const int tid = threadIdx.x;
  const int q = tid & 3, r = tid >> 2;     // 4-way K-split, 128 rows/slice
  const int R = (s << 7) + r;
  __shared__ __align__(16) unsigned int lds[4 * 132];   // 132-uint padded chunks: conflict-free b128 reads

  // weights: 128 half2 per thread, register-resident
  uint4 wreg[32];
  #pragma unroll
  for (int j = 0; j < 32; ++j) wreg[j] = Wp4[(long)(s * 32 + j) * 512 + tid];

  const float b0r = b0[R];
  const bool isV = (s >= 4);
  unsigned int* SstU = (unsigned int*)Sst;
  const unsigned int* lp = lds + q * 132;

  for (int t = 1; t < 1024; ++t) {
    // prefetch bias (read-only, precomputed)
    float bsv = (float)bHV[((long)(t - 1) * 32 + b) * 1024 + R];

    if (t > 1) {
      while (__hip_atomic_load(&cnt[(t - 1) * 32 + b], __ATOMIC_ACQUIRE,
                               __HIP_MEMORY_SCOPE_AGENT) < 8u)
        __builtin_amdgcn_s_sleep(1);
    }
    // cooperative coherent load of prev state row (512 uints = 1024 f16)
    unsigned int sv = __hip_atomic_load(&SstU[((long)(t - 1) * 32 + b) * 512 + tid],
                                        __ATOMIC_RELAXED, __HIP_MEMORY_SCOPE_AGENT);
    lds[(tid >> 7) * 132 + (tid & 127)] = sv;
    __syncthreads();

    float acc = 0.0f;
    #pragma unroll
    for (int jj = 0; jj < 32; ++jj) {
      uint4 s4 = *(const uint4*)(lp + jj * 4);
      acc = fdot2u(s4.x, wreg[jj].x, acc);
      acc = fdot2u(s4.y, wreg[jj].y, acc);
      acc = fdot2u(s4.z, wreg[jj].z, acc);
      acc = fdot2u(s4.w, wreg[jj].w, acc);
    }
    // reduce the 4 K-chunks (adjacent lanes)
    acc += __shfl_xor(acc, 1, 64);
    acc += __shfl_xor(acc, 2, 64);

    float val = acc + bsv + b0r;
    if (isV) val = fmaxf(val, 0.0f);
    f16 hv = (f16)val;
    unsigned int hb = (unsigned int)__builtin_bit_cast(unsigned short, hv);
    unsigned int nb = __shfl_down(hb, 4, 64);   // row r+1's value
    if ((tid & 7) == 0) {
      __hip_atomic_store(&SstU[((long)t * 32 + b) * 512 + (R >> 1)], hb | (nb << 16),
                         __ATOMIC_RELAXED, __HIP_MEMORY_SCOPE_AGENT);
    }
    __syncthreads();                            // drains vmcnt for all waves before flag
    if (tid == 0) atomicAdd(&cnt[t * 32 + b], 1u);
  }
}

// C32 [b][t][j] f32 -> out [b][j][t]
__global__ void k_trout(const float* __restrict__ C, float* __restrict__ out) {
  __shared__ float tile[64][65];
  int b = blockIdx.y, t0 = blockIdx.x << 6;
  int tid = threadIdx.x;
  #pragma unroll
  for (int it = 0; it < 16; ++it) {
    int idx = it * 256 + tid; int tt = idx >> 6, j = idx & 63;
    tile[j][tt] = C[((long)b * 1024 + t0 + tt) * 64 + j];
  }
  __syncthreads();
  #pragma unroll
  for (int it = 0; it < 16; ++it) {
    int idx = it * 256 + tid; int j = idx >> 6, tt = idx & 63;
    out[((long)b * 64 + j) * 1024 + t0 + tt] = tile[j][tt];
  }
}

// ============ host ============
extern "C" void kernel_launch(void* const* d_in, const int* in_sizes, int n_in,
                              void* d_out, int out_size, void* d_ws, size_t ws_size,
                              hipStream_t stream) {
  (void)in_sizes; (void)n_in; (void)out_size; (void)ws_size;
  const float* u   = (const float*)d_in[0];
  const float* E   = (const float*)d_in[1];
  const float* Fw  = (const float*)d_in[2];
  const float* Fb  = (const float*)d_in[3];
  const float* B1w = (const float*)d_in[4];
  const float* B2w = (const float*)d_in[5];
  const float* C2t = (const float*)d_in[6];
  const float* bv  = (const float*)d_in[7];
  const float* Dt  = (const float*)d_in[8];
  const float* C1w = (const float*)d_in[9];
  const float* D11 = (const float*)d_in[10];
  const float* D12 = (const float*)d_in[11];
  const float* by  = (const float*)d_in[12];
  const float* mul = (const float*)d_in[13];
  float* out = (float*)d_out;

  char* w = (char*)d_ws;
  size_t off = 0;
  auto alloc = [&](size_t bytes) { size_t o = off; off += (bytes + 255) & ~(size_t)255; return o; };

  f16*  UP    = (f16*)(w + alloc(1025L * 32 * 64 * 2));  // u packed [t][b][nu], padded t=1024 row
  f16*  E16   = (f16*)(w + alloc(262144L * 2));
  f16*  F16   = (f16*)(w + alloc(262144L * 2));
  f16*  B116  = (f16*)(w + alloc(262144L * 2));
  f16*  B216  = (f16*)(w + alloc(32768L * 2));
  f16*  CV16  = (f16*)(w + alloc(262144L * 2));
  f16*  DVT   = (f16*)(w + alloc(32768L * 2));
  f16*  XA    = (f16*)(w + alloc(262144L * 2));
  f16*  XB    = (f16*)(w + alloc(262144L * 2));
  f16*  Z16   = (f16*)(w + alloc(262144L * 2));
  float* Y32  = (float*)(w + alloc(262144L * 4));
  f16*  A1    = (f16*)(w + alloc(262144L * 2));
  f16*  A2    = (f16*)(w + alloc(262144L * 2));
  f16*  A3    = (f16*)(w + alloc(32768L * 2));
  f16*  M1    = (f16*)(w + alloc(262144L * 2));
  f16*  M2    = (f16*)(w + alloc(262144L * 2));
  f16*  CVA3  = (f16*)(w + alloc(32768L * 2));
  f16*  A3T   = (f16*)(w + alloc(32768L * 2));
  f16*  CVA3T = (f16*)(w + alloc(32768L * 2));
  unsigned int* WPK = (unsigned int*)(w + alloc(524288L * 4));
  f16*  WOUT  = (f16*)(w + alloc(69632L * 2));           // 1088x64
  float* CB   = (float*)(w + alloc(512L * 4));
  float* B0   = (float*)(w + alloc(1024L * 4));
  f16*  BHV   = (f16*)(w + alloc(1024L * 32 * 1024 * 2));  // per-step input biases [t][b][1024]
  f16*  SST   = (f16*)(w + alloc(1024L * 32 * 1024 * 2));  // state history [t][b][1024]
  unsigned int* CNT = (unsigned int*)(w + alloc(32768L * 4));
  float* C32  = (float*)(w + alloc(2097152L * 4));         // y pre-transpose [b][t][64]

  // init
  hipMemsetAsync(UP, 0, 1025L * 32 * 64 * 2, stream);
  hipMemsetAsync(CNT, 0, 32768L * 4, stream);
  hipMemsetAsync(SST, 0, 32L * 1024 * 2, stream);          // h0 = 0 (w0 overwritten below)

  k_packu<<<dim3(16, 32), 256, 0, stream>>>(u, UP);
  k_cvt<<<1024, 256, 0, stream>>>(E, E16, 262144);
  k_cvt<<<1024, 256, 0, stream>>>(Fw, F16, 262144);
  k_cvt<<<1024, 256, 0, stream>>>(B1w, B116, 262144);
  k_cvt<<<128, 256, 0, stream>>>(B2w, B216, 32768);
  k_build_cv<<<1024, 256, 0, stream>>>(C2t, mul, CV16);
  k_build_dvt<<<128, 256, 0, stream>>>(Dt, mul, DVT);

  // Newton: X <- X(2I - E X), X0 = 2I - E (4 iters, f16 storage, f32 accum)
  k_2im<<<1024, 256, 0, stream>>>(E, XA);
  f16 *X = XA, *Xo = XB;
  for (int it = 0; it < 4; ++it) {
    gemm16<0,0,0,0><<<dim3(8,8,1), 256, 0, stream>>>(E16, 512, 0, X, 512, Y32, 512, 0, nullptr, 512, 512, 512);
    k_2im<<<1024, 256, 0, stream>>>(Y32, Z16);
    gemm16<1,0,0,0><<<dim3(8,8,1), 256, 0, stream>>>(X, 512, 0, Z16, 512, Xo, 512, 0, nullptr, 512, 512, 512);
    f16* tmp = X; X = Xo; Xo = tmp;
  }

  // fused weights
  gemm16<1,0,0,0><<<dim3(8,8,1), 256, 0, stream>>>(X, 512, 0, F16, 512, A1, 512, 0, nullptr, 512, 512, 512);
  gemm16<1,0,0,0><<<dim3(8,8,1), 256, 0, stream>>>(X, 512, 0, B116, 512, A2, 512, 0, nullptr, 512, 512, 512);
  gemm16<1,0,0,0><<<dim3(8,1,1), 256, 0, stream>>>(X, 512, 0, B216, 64, A3, 64, 0, nullptr, 512, 64, 512);
  gemm16<1,0,0,0><<<dim3(8,8,1), 256, 0, stream>>>(CV16, 512, 0, A1, 512, M1, 512, 0, nullptr, 512, 512, 512);
  gemm16<1,0,0,0><<<dim3(8,8,1), 256, 0, stream>>>(CV16, 512, 0, A2, 512, M2, 512, 0, nullptr, 512, 512, 512);
  gemm16<1,0,0,0><<<dim3(8,1,1), 256, 0, stream>>>(CV16, 512, 0, A3, 64, CVA3, 64, 0, nullptr, 512, 64, 512);
  k_tr16<<<128, 256, 0, stream>>>(A3, A3T, 512, 64);
  k_tr16<<<128, 256, 0, stream>>>(CVA3, CVA3T, 512, 64);
  k_woutt<<<272, 256, 0, stream>>>(C1w, D11, D12, WOUT);
  k_cb<<<1, 512, 0, stream>>>(X, Fb, CB);
  k_bias0<<<2, 512, 0, stream>>>(CV16, CB, bv, B0);
  k_packw<<<2048, 256, 0, stream>>>(A1, A2, M1, M2, WPK);

  // per-step input biases: biasH[t] = u_t @ A3T ; biasV[t] = u_t @ CvA3T + u_{t+1} @ DvT
  gemm16<1,0,0,0><<<dim3(512,8,1), 256, 0, stream>>>(UP, 64, 0, A3T, 512, BHV, 1024, 0, nullptr, 32768, 512, 64);
  gemm16<1,0,0,0><<<dim3(512,8,1), 256, 0, stream>>>(UP, 64, 0, CVA3T, 512, BHV + 512, 1024, 0, nullptr, 32768, 512, 64);
  gemm16<1,1,0,0><<<dim3(512,8,1), 256, 0, stream>>>(UP + 2048, 64, 0, DVT, 512, BHV + 512, 1024, 0, nullptr, 32768, 512, 64);
  // w0 = relu(u_0 @ DvT + bv) -> Sst[0][b][512:]
  gemm16<1,0,1,1><<<dim3(1,8,1), 256, 0, stream>>>(UP, 64, 0, DVT, 512, SST + 512, 1024, 0, bv, 32, 512, 64);

  // the sequential recurrence
  k_scan<<<256, 512, 0, stream>>>((const uint4*)WPK, BHV, B0, SST, CNT);

  // y = [h;w] @ WoutT[0:1024] + u @ WoutT[1024:1088] + by   (batched over b)
  gemm16<0,0,0,0><<<dim3(16,1,32), 256, 0, stream>>>(SST, 32768, 1024, WOUT, 64, C32, 64, 65536, nullptr, 1024, 64, 1024);
  gemm16<0,1,0,1><<<dim3(16,1,32), 256, 0, stream>>>(UP, 2048, 64, WOUT + 65536, 64, C32, 64, 65536, by, 1024, 64, 64);
  k_trout<<<dim3(16, 32), 256, 0, stream>>>(C32, out);
}

// Round 3
// 17483.904 us; speedup vs baseline: 1.5767x; 1.5767x over previous
//
#include <hip/hip_runtime.h>

typedef _Float16 f16;
typedef _Float16 h2_t __attribute__((ext_vector_type(2)));
typedef _Float16 h8_t __attribute__((ext_vector_type(8)));
typedef float    f4_t __attribute__((ext_vector_type(4)));

__device__ __forceinline__ float fdot2u(unsigned int a, unsigned int b, float c) {
  return __builtin_amdgcn_fdot2(__builtin_bit_cast(h2_t, a),
                                __builtin_bit_cast(h2_t, b), c, false);
}

// ============ generic f16-input MFMA GEMM: C[z] = A[z] @ B (+bias)(+accum)(+relu) ============
// C/D layout: col = lane&15, row = (lane>>4)*4 + reg   [m89-verified]
template<int F16OUT, int ACCUM, int RELU, int BIASF>
__global__ __launch_bounds__(256) void gemm16(
    const f16* __restrict__ Ap, long lda, long sAz,
    const f16* __restrict__ Bp, long ldb,
    void* __restrict__ Cp, long ldc, long sCz,
    const float* __restrict__ biasN,
    int M, int N, int K)
{
  const int lane = threadIdx.x & 63;
  const int wv   = threadIdx.x >> 6;
  const int rl = lane & 15, kb = lane >> 4;
  const long z = blockIdx.z;
  const f16* Az = Ap + z * sAz;
  const int rowA = blockIdx.x * 64 + wv * 16 + rl;
  const long rA = (rowA < M) ? rowA : 0;
  const int colBase = blockIdx.y * 64;
  f4_t acc[4];
  #pragma unroll
  for (int c = 0; c < 4; ++c) acc[c] = 0.0f;

  for (int k0 = 0; k0 < K; k0 += 32) {
    h8_t af = *(const h8_t*)(Az + rA * lda + (k0 + kb * 8));
    h8_t bf[4];
    #pragma unroll
    for (int i = 0; i < 8; ++i) {
      long krow = (long)(k0 + kb * 8 + i) * ldb + colBase + rl;
      #pragma unroll
      for (int c = 0; c < 4; ++c) bf[c][i] = Bp[krow + 16 * c];
    }
    #pragma unroll
    for (int c = 0; c < 4; ++c)
      acc[c] = __builtin_amdgcn_mfma_f32_16x16x32_f16(af, bf[c], acc[c], 0, 0, 0);
  }

  #pragma unroll
  for (int c = 0; c < 4; ++c) {
    const int col = colBase + c * 16 + rl;
    #pragma unroll
    for (int g = 0; g < 4; ++g) {
      const int row = blockIdx.x * 64 + wv * 16 + kb * 4 + g;
      if (row < M) {
        float v = acc[c][g];
        const long ci = z * sCz + (long)row * ldc + col;
        if (BIASF) v += biasN[col];
        if (ACCUM) v += F16OUT ? (float)((const f16*)Cp)[ci] : ((const float*)Cp)[ci];
        if (RELU) v = fmaxf(v, 0.0f);
        if (F16OUT) ((f16*)Cp)[ci] = (f16)v;
        else        ((float*)Cp)[ci] = v;
      }
    }
  }
}

// ============ small helper kernels ============
__global__ void k_cvt(const float* __restrict__ s, f16* __restrict__ d, int n) {
  int i = blockIdx.x * 256 + threadIdx.x;
  if (i < n) d[i] = (f16)s[i];
}

__global__ void k_build_cv(const float* __restrict__ C2, const float* __restrict__ mul,
                           f16* __restrict__ cv) {
  int i = blockIdx.x * 256 + threadIdx.x;   // 512*512
  int r = i >> 9;
  cv[i] = (f16)(C2[i] / mul[r]);
}

__global__ void k_build_dvt(const float* __restrict__ Dt, const float* __restrict__ mul,
                            f16* __restrict__ dvt) {
  int i = blockIdx.x * 256 + threadIdx.x;   // 64*512
  int k = i >> 9, n = i & 511;
  dvt[i] = (f16)(Dt[n * 64 + k] / mul[n]);
}

__global__ void k_2im(const float* __restrict__ s, f16* __restrict__ d) {
  int i = blockIdx.x * 256 + threadIdx.x;
  int r = i >> 9, c = i & 511;
  d[i] = (f16)(((r == c) ? 2.0f : 0.0f) - s[i]);
}

__global__ void k_tr16(const f16* __restrict__ s, f16* __restrict__ d, int R, int C) {
  int i = blockIdx.x * 256 + threadIdx.x;
  if (i < R * C) { int j = i / R, r = i % R; d[i] = s[r * C + j]; }
}

__global__ void k_woutt(const float* __restrict__ C1, const float* __restrict__ D11,
                        const float* __restrict__ D12, f16* __restrict__ Wo) {
  int i = blockIdx.x * 256 + threadIdx.x;   // 1088*64
  int k = i >> 6, j = i & 63;
  float v = (k < 512) ? C1[j * 512 + k]
          : (k < 1024) ? D11[j * 512 + (k - 512)]
                       : D12[j * 64 + (k - 1024)];
  Wo[i] = (f16)v;
}

__global__ void k_cb(const f16* __restrict__ X, const float* __restrict__ Fb,
                     float* __restrict__ cb) {
  int i = threadIdx.x;
  float a = 0.0f;
  for (int k = 0; k < 512; ++k) a += (float)X[i * 512 + k] * Fb[k];
  cb[i] = a;
}

__global__ void k_bias0(const f16* __restrict__ Cv, const float* __restrict__ cb,
                        const float* __restrict__ bv, float* __restrict__ b0) {
  int i = blockIdx.x * 512 + threadIdx.x;
  if (i < 512) b0[i] = cb[i];
  else {
    int j = i - 512;
    float a = bv[j];
    for (int k = 0; k < 512; ++k) a += (float)Cv[j * 512 + k] * cb[k];
    b0[i] = a;
  }
}

__global__ void k_packu(const float* __restrict__ u, f16* __restrict__ up) {
  __shared__ f16 tile[64][65];
  int b = blockIdx.y, t0 = blockIdx.x << 6;
  int tid = threadIdx.x;
  #pragma unroll
  for (int it = 0; it < 16; ++it) {
    int idx = it * 256 + tid; int i = idx >> 6, tt = idx & 63;
    tile[tt][i] = (f16)u[((long)b * 64 + i) * 1024 + t0 + tt];
  }
  __syncthreads();
  #pragma unroll
  for (int it = 0; it < 16; ++it) {
    int idx = it * 256 + tid; int tt = idx >> 6, i = idx & 63;
    up[((long)(t0 + tt) * 32 + b) * 64 + i] = tile[tt][i];
  }
}

// Pack Wbig = [[A1 A2],[M1 M2]] (1024x1024 f16) into per-thread register layout.
__global__ void k_packw(const f16* __restrict__ A1, const f16* __restrict__ A2,
                        const f16* __restrict__ M1, const f16* __restrict__ M2,
                        unsigned int* __restrict__ Wp) {
  int U = blockIdx.x * 256 + threadIdx.x;   // 524288
  int p = U & 3; int V = U >> 2;
  int tid = V & 511; int sj = V >> 9;
  int jj = sj & 31; int s = sj >> 5;
  int q = tid & 3, r = tid >> 2;
  int R = s * 128 + r;
  int k = q * 256 + jj * 8 + p * 2;
  f16 g0, g1;
  if (R < 512) {
    if (k < 512) { g0 = A1[R * 512 + k];         g1 = A1[R * 512 + k + 1]; }
    else         { g0 = A2[R * 512 + k - 512];   g1 = A2[R * 512 + k - 511]; }
  } else {
    int Rm = R - 512;
    if (k < 512) { g0 = M1[Rm * 512 + k];        g1 = M1[Rm * 512 + k + 1]; }
    else         { g0 = M2[Rm * 512 + k - 512];  g1 = M2[Rm * 512 + k - 511]; }
  }
  unsigned int lo = __builtin_bit_cast(unsigned short, g0);
  unsigned int hi = __builtin_bit_cast(unsigned short, g1);
  Wp[U] = lo | (hi << 16);
}

// ============ the sequential scan: persistent, 256 WGs = 32 batches x 8 slices ============
// Sync: per-(t,b) line-padded store-only flags (no RMW). Producer WG (s,b):
// barrier(drain) -> release-store flg[(t*32+b)*32+s]=1. Consumer wave: relaxed spin on the
// 8 contiguous flags (lanes 0-7, one coalesced request/iter) -> acquire fence -> state load.
__global__ __launch_bounds__(512, 1) void k_scan(
    const uint4* __restrict__ Wp4,
    const f16* __restrict__ bHV,
    const float* __restrict__ b0,
    f16* __restrict__ Sst,
    unsigned int* __restrict__ flg)
{
  const int wg = blockIdx.x;
  const int s = wg >> 5, b = wg & 31;
  const int tid = threadIdx.x;
  const int q = tid & 3, r = tid >> 2;     // 4-way K-split, 128 rows/slice
  const int R = (s << 7) + r;
  const int lane = tid & 63;
  __shared__ __align__(16) unsigned int lds[4 * 132];

  // weights: 128 VGPRs/thread, register-resident (launch_bounds(512,1) -> 256-VGPR budget)
  uint4 wreg[32];
  #pragma unroll
  for (int j = 0; j < 32; ++j) wreg[j] = Wp4[(long)(s * 32 + j) * 512 + tid];

  const float b0r = b0[R];
  const bool isV = (s >= 4);
  unsigned int* SstU = (unsigned int*)Sst;
  const unsigned int* lp = lds + q * 132;

  for (int t = 1; t < 1024; ++t) {
    // bias prefetch (independent, completes during poll)
    float bsv = (float)bHV[((long)(t - 1) * 32 + b) * 1024 + R];

    if (t > 1) {
      const unsigned int* fp = flg + ((long)(t - 1) * 32 + b) * 32;
      for (;;) {
        unsigned int v = 1u;
        if (lane < 8)
          v = __hip_atomic_load(fp + lane, __ATOMIC_RELAXED, __HIP_MEMORY_SCOPE_AGENT);
        if (__all(v != 0u)) break;
        __builtin_amdgcn_s_sleep(1);
      }
      __builtin_amdgcn_fence(__ATOMIC_ACQUIRE, "agent");
    }
    // cooperative coherent load of prev state row (512 dwords = 1024 f16)
    unsigned int sv = __hip_atomic_load(&SstU[((long)(t - 1) * 32 + b) * 512 + tid],
                                        __ATOMIC_RELAXED, __HIP_MEMORY_SCOPE_AGENT);
    lds[(tid >> 7) * 132 + (tid & 127)] = sv;
    __syncthreads();

    float acc = 0.0f;
    #pragma unroll
    for (int jj = 0; jj < 32; ++jj) {
      uint4 s4 = *(const uint4*)(lp + jj * 4);
      acc = fdot2u(s4.x, wreg[jj].x, acc);
      acc = fdot2u(s4.y, wreg[jj].y, acc);
      acc = fdot2u(s4.z, wreg[jj].z, acc);
      acc = fdot2u(s4.w, wreg[jj].w, acc);
    }
    acc += __shfl_xor(acc, 1, 64);
    acc += __shfl_xor(acc, 2, 64);

    float val = acc + bsv + b0r;
    if (isV) val = fmaxf(val, 0.0f);
    f16 hv = (f16)val;
    unsigned int hb = (unsigned int)__builtin_bit_cast(unsigned short, hv);
    unsigned int nb = __shfl_down(hb, 4, 64);   // row r+1's value
    if ((tid & 7) == 0) {
      __hip_atomic_store(&SstU[((long)t * 32 + b) * 512 + (R >> 1)], hb | (nb << 16),
                         __ATOMIC_RELAXED, __HIP_MEMORY_SCOPE_AGENT);
    }
    __syncthreads();   // per-wave vmcnt(0) drain before barrier => slice globally visible
    if (tid == 0)
      __hip_atomic_store(flg + ((long)t * 32 + b) * 32 + s, 1u,
                         __ATOMIC_RELEASE, __HIP_MEMORY_SCOPE_AGENT);
  }
}

// C32 [b][t][j] f32 -> out [b][j][t]
__global__ void k_trout(const float* __restrict__ C, float* __restrict__ out) {
  __shared__ float tile[64][65];
  int b = blockIdx.y, t0 = blockIdx.x << 6;
  int tid = threadIdx.x;
  #pragma unroll
  for (int it = 0; it < 16; ++it) {
    int idx = it * 256 + tid; int tt = idx >> 6, j = idx & 63;
    tile[j][tt] = C[((long)b * 1024 + t0 + tt) * 64 + j];
  }
  __syncthreads();
  #pragma unroll
  for (int it = 0; it < 16; ++it) {
    int idx = it * 256 + tid; int j = idx >> 6, tt = idx & 63;
    out[((long)b * 64 + j) * 1024 + t0 + tt] = tile[j][tt];
  }
}

// ============ host ============
extern "C" void kernel_launch(void* const* d_in, const int* in_sizes, int n_in,
                              void* d_out, int out_size, void* d_ws, size_t ws_size,
                              hipStream_t stream) {
  (void)in_sizes; (void)n_in; (void)out_size; (void)ws_size;
  const float* u   = (const float*)d_in[0];
  const float* E   = (const float*)d_in[1];
  const float* Fw  = (const float*)d_in[2];
  const float* Fb  = (const float*)d_in[3];
  const float* B1w = (const float*)d_in[4];
  const float* B2w = (const float*)d_in[5];
  const float* C2t = (const float*)d_in[6];
  const float* bv  = (const float*)d_in[7];
  const float* Dt  = (const float*)d_in[8];
  const float* C1w = (const float*)d_in[9];
  const float* D11 = (const float*)d_in[10];
  const float* D12 = (const float*)d_in[11];
  const float* by  = (const float*)d_in[12];
  const float* mul = (const float*)d_in[13];
  float* out = (float*)d_out;

  char* w = (char*)d_ws;
  size_t off = 0;
  auto alloc = [&](size_t bytes) { size_t o = off; off += (bytes + 255) & ~(size_t)255; return o; };

  f16*  UP    = (f16*)(w + alloc(1025L * 32 * 64 * 2));  // u packed [t][b][nu], padded t=1024 row
  f16*  E16   = (f16*)(w + alloc(262144L * 2));
  f16*  F16   = (f16*)(w + alloc(262144L * 2));
  f16*  B116  = (f16*)(w + alloc(262144L * 2));
  f16*  B216  = (f16*)(w + alloc(32768L * 2));
  f16*  CV16  = (f16*)(w + alloc(262144L * 2));
  f16*  DVT   = (f16*)(w + alloc(32768L * 2));
  f16*  XA    = (f16*)(w + alloc(262144L * 2));
  f16*  XB    = (f16*)(w + alloc(262144L * 2));
  f16*  Z16   = (f16*)(w + alloc(262144L * 2));
  float* Y32  = (float*)(w + alloc(262144L * 4));
  f16*  A1    = (f16*)(w + alloc(262144L * 2));
  f16*  A2    = (f16*)(w + alloc(262144L * 2));
  f16*  A3    = (f16*)(w + alloc(32768L * 2));
  f16*  M1    = (f16*)(w + alloc(262144L * 2));
  f16*  M2    = (f16*)(w + alloc(262144L * 2));
  f16*  CVA3  = (f16*)(w + alloc(32768L * 2));
  f16*  A3T   = (f16*)(w + alloc(32768L * 2));
  f16*  CVA3T = (f16*)(w + alloc(32768L * 2));
  unsigned int* WPK = (unsigned int*)(w + alloc(524288L * 4));
  f16*  WOUT  = (f16*)(w + alloc(69632L * 2));           // 1088x64
  float* CB   = (float*)(w + alloc(512L * 4));
  float* B0   = (float*)(w + alloc(1024L * 4));
  f16*  BHV   = (f16*)(w + alloc(1024L * 32 * 1024 * 2));  // per-step input biases [t][b][1024]
  f16*  SST   = (f16*)(w + alloc(1024L * 32 * 1024 * 2));  // state history [t][b][1024]
  float* C32  = (float*)(w + alloc(2097152L * 4));         // y pre-transpose [b][t][64]
  // FLG aliases C32: flags used only during k_scan; C32 written only after k_scan.
  unsigned int* FLG = (unsigned int*)C32;                  // [t][b][32] line-padded, 4 MB

  // init (every call: ws is re-poisoned before each timed launch)
  (void)hipMemsetAsync(UP, 0, 1025L * 32 * 64 * 2, stream);
  (void)hipMemsetAsync(FLG, 0, 1024L * 32 * 32 * 4, stream);
  (void)hipMemsetAsync(SST, 0, 32L * 1024 * 2, stream);    // h0 = 0 (w0 overwritten below)

  k_packu<<<dim3(16, 32), 256, 0, stream>>>(u, UP);
  k_cvt<<<1024, 256, 0, stream>>>(E, E16, 262144);
  k_cvt<<<1024, 256, 0, stream>>>(Fw, F16, 262144);
  k_cvt<<<1024, 256, 0, stream>>>(B1w, B116, 262144);
  k_cvt<<<128, 256, 0, stream>>>(B2w, B216, 32768);
  k_build_cv<<<1024, 256, 0, stream>>>(C2t, mul, CV16);
  k_build_dvt<<<128, 256, 0, stream>>>(Dt, mul, DVT);

  // Newton: X <- X(2I - E X), X0 = 2I - E (4 iters, f16 storage, f32 accum)
  k_2im<<<1024, 256, 0, stream>>>(E, XA);
  f16 *X = XA, *Xo = XB;
  for (int it = 0; it < 4; ++it) {
    gemm16<0,0,0,0><<<dim3(8,8,1), 256, 0, stream>>>(E16, 512, 0, X, 512, Y32, 512, 0, nullptr, 512, 512, 512);
    k_2im<<<1024, 256, 0, stream>>>(Y32, Z16);
    gemm16<1,0,0,0><<<dim3(8,8,1), 256, 0, stream>>>(X, 512, 0, Z16, 512, Xo, 512, 0, nullptr, 512, 512, 512);
    f16* tmp = X; X = Xo; Xo = tmp;
  }

  // fused weights
  gemm16<1,0,0,0><<<dim3(8,8,1), 256, 0, stream>>>(X, 512, 0, F16, 512, A1, 512, 0, nullptr, 512, 512, 512);
  gemm16<1,0,0,0><<<dim3(8,8,1), 256, 0, stream>>>(X, 512, 0, B116, 512, A2, 512, 0, nullptr, 512, 512, 512);
  gemm16<1,0,0,0><<<dim3(8,1,1), 256, 0, stream>>>(X, 512, 0, B216, 64, A3, 64, 0, nullptr, 512, 64, 512);
  gemm16<1,0,0,0><<<dim3(8,8,1), 256, 0, stream>>>(CV16, 512, 0, A1, 512, M1, 512, 0, nullptr, 512, 512, 512);
  gemm16<1,0,0,0><<<dim3(8,8,1), 256, 0, stream>>>(CV16, 512, 0, A2, 512, M2, 512, 0, nullptr, 512, 512, 512);
  gemm16<1,0,0,0><<<dim3(8,1,1), 256, 0, stream>>>(CV16, 512, 0, A3, 64, CVA3, 64, 0, nullptr, 512, 64, 512);
  k_tr16<<<128, 256, 0, stream>>>(A3, A3T, 512, 64);
  k_tr16<<<128, 256, 0, stream>>>(CVA3, CVA3T, 512, 64);
  k_woutt<<<272, 256, 0, stream>>>(C1w, D11, D12, WOUT);
  k_cb<<<1, 512, 0, stream>>>(X, Fb, CB);
  k_bias0<<<2, 512, 0, stream>>>(CV16, CB, bv, B0);
  k_packw<<<2048, 256, 0, stream>>>(A1, A2, M1, M2, WPK);

  // per-step input biases: biasH[t] = u_t @ A3T ; biasV[t] = u_t @ CvA3T + u_{t+1} @ DvT
  gemm16<1,0,0,0><<<dim3(512,8,1), 256, 0, stream>>>(UP, 64, 0, A3T, 512, BHV, 1024, 0, nullptr, 32768, 512, 64);
  gemm16<1,0,0,0><<<dim3(512,8,1), 256, 0, stream>>>(UP, 64, 0, CVA3T, 512, BHV + 512, 1024, 0, nullptr, 32768, 512, 64);
  gemm16<1,1,0,0><<<dim3(512,8,1), 256, 0, stream>>>(UP + 2048, 64, 0, DVT, 512, BHV + 512, 1024, 0, nullptr, 32768, 512, 64);
  // w0 = relu(u_0 @ DvT + bv) -> Sst[0][b][512:]
  gemm16<1,0,1,1><<<dim3(1,8,1), 256, 0, stream>>>(UP, 64, 0, DVT, 512, SST + 512, 1024, 0, bv, 32, 512, 64);

  // the sequential recurrence
  k_scan<<<256, 512, 0, stream>>>((const uint4*)WPK, BHV, B0, SST, FLG);

  // y = [h;w] @ WoutT[0:1024] + u @ WoutT[1024:1088] + by   (batched over b)
  gemm16<0,0,0,0><<<dim3(16,1,32), 256, 0, stream>>>(SST, 32768, 1024, WOUT, 64, C32, 64, 65536, nullptr, 1024, 64, 1024);
  gemm16<0,1,0,1><<<dim3(16,1,32), 256, 0, stream>>>(UP, 2048, 64, WOUT + 65536, 64, C32, 64, 65536, by, 1024, 64, 64);
  k_trout<<<dim3(16, 32), 256, 0, stream>>>(C32, out);
}

// Round 4
// 2153.563 us; speedup vs baseline: 12.8005x; 8.1186x over previous
//
#include <hip/hip_runtime.h>

typedef _Float16 f16;
typedef _Float16 h2_t __attribute__((ext_vector_type(2)));
typedef _Float16 h8_t __attribute__((ext_vector_type(8)));
typedef float    f4_t __attribute__((ext_vector_type(4)));

__device__ __forceinline__ float fdot2u(unsigned int a, unsigned int b, float c) {
  return __builtin_amdgcn_fdot2(__builtin_bit_cast(h2_t, a),
                                __builtin_bit_cast(h2_t, b), c, false);
}

// ============ generic f16-input MFMA GEMM: C[z] = A[z] @ B (+bias)(+accum)(+relu) ============
// C/D layout: col = lane&15, row = (lane>>4)*4 + reg   [m89-verified]
template<int F16OUT, int ACCUM, int RELU, int BIASF>
__global__ __launch_bounds__(256) void gemm16(
    const f16* __restrict__ Ap, long lda, long sAz,
    const f16* __restrict__ Bp, long ldb,
    void* __restrict__ Cp, long ldc, long sCz,
    const float* __restrict__ biasN,
    int M, int N, int K)
{
  const int lane = threadIdx.x & 63;
  const int wv   = threadIdx.x >> 6;
  const int rl = lane & 15, kb = lane >> 4;
  const long z = blockIdx.z;
  const f16* Az = Ap + z * sAz;
  const int rowA = blockIdx.x * 64 + wv * 16 + rl;
  const long rA = (rowA < M) ? rowA : 0;
  const int colBase = blockIdx.y * 64;
  f4_t acc[4];
  #pragma unroll
  for (int c = 0; c < 4; ++c) acc[c] = 0.0f;

  for (int k0 = 0; k0 < K; k0 += 32) {
    h8_t af = *(const h8_t*)(Az + rA * lda + (k0 + kb * 8));
    h8_t bf[4];
    #pragma unroll
    for (int i = 0; i < 8; ++i) {
      long krow = (long)(k0 + kb * 8 + i) * ldb + colBase + rl;
      #pragma unroll
      for (int c = 0; c < 4; ++c) bf[c][i] = Bp[krow + 16 * c];
    }
    #pragma unroll
    for (int c = 0; c < 4; ++c)
      acc[c] = __builtin_amdgcn_mfma_f32_16x16x32_f16(af, bf[c], acc[c], 0, 0, 0);
  }

  #pragma unroll
  for (int c = 0; c < 4; ++c) {
    const int col = colBase + c * 16 + rl;
    #pragma unroll
    for (int g = 0; g < 4; ++g) {
      const int row = blockIdx.x * 64 + wv * 16 + kb * 4 + g;
      if (row < M) {
        float v = acc[c][g];
        const long ci = z * sCz + (long)row * ldc + col;
        if (BIASF) v += biasN[col];
        if (ACCUM) v += F16OUT ? (float)((const f16*)Cp)[ci] : ((const float*)Cp)[ci];
        if (RELU) v = fmaxf(v, 0.0f);
        if (F16OUT) ((f16*)Cp)[ci] = (f16)v;
        else        ((float*)Cp)[ci] = v;
      }
    }
  }
}

// ============ small helper kernels ============
__global__ void k_cvt(const float* __restrict__ s, f16* __restrict__ d, int n) {
  int i = blockIdx.x * 256 + threadIdx.x;
  if (i < n) d[i] = (f16)s[i];
}

__global__ void k_build_cv(const float* __restrict__ C2, const float* __restrict__ mul,
                           f16* __restrict__ cv) {
  int i = blockIdx.x * 256 + threadIdx.x;   // 512*512
  int r = i >> 9;
  cv[i] = (f16)(C2[i] / mul[r]);
}

__global__ void k_build_dvt(const float* __restrict__ Dt, const float* __restrict__ mul,
                            f16* __restrict__ dvt) {
  int i = blockIdx.x * 256 + threadIdx.x;   // 64*512
  int k = i >> 9, n = i & 511;
  dvt[i] = (f16)(Dt[n * 64 + k] / mul[n]);
}

__global__ void k_2im(const float* __restrict__ s, f16* __restrict__ d) {
  int i = blockIdx.x * 256 + threadIdx.x;
  int r = i >> 9, c = i & 511;
  d[i] = (f16)(((r == c) ? 2.0f : 0.0f) - s[i]);
}

__global__ void k_tr16(const f16* __restrict__ s, f16* __restrict__ d, int R, int C) {
  int i = blockIdx.x * 256 + threadIdx.x;
  if (i < R * C) { int j = i / R, r = i % R; d[i] = s[r * C + j]; }
}

__global__ void k_woutt(const float* __restrict__ C1, const float* __restrict__ D11,
                        const float* __restrict__ D12, f16* __restrict__ Wo) {
  int i = blockIdx.x * 256 + threadIdx.x;   // 1088*64
  int k = i >> 6, j = i & 63;
  float v = (k < 512) ? C1[j * 512 + k]
          : (k < 1024) ? D11[j * 512 + (k - 512)]
                       : D12[j * 64 + (k - 1024)];
  Wo[i] = (f16)v;
}

__global__ void k_cb(const f16* __restrict__ X, const float* __restrict__ Fb,
                     float* __restrict__ cb) {
  int i = threadIdx.x;
  float a = 0.0f;
  for (int k = 0; k < 512; ++k) a += (float)X[i * 512 + k] * Fb[k];
  cb[i] = a;
}

__global__ void k_bias0(const f16* __restrict__ Cv, const float* __restrict__ cb,
                        const float* __restrict__ bv, float* __restrict__ b0) {
  int i = blockIdx.x * 512 + threadIdx.x;
  if (i < 512) b0[i] = cb[i];
  else {
    int j = i - 512;
    float a = bv[j];
    for (int k = 0; k < 512; ++k) a += (float)Cv[j * 512 + k] * cb[k];
    b0[i] = a;
  }
}

__global__ void k_packu(const float* __restrict__ u, f16* __restrict__ up) {
  __shared__ f16 tile[64][65];
  int b = blockIdx.y, t0 = blockIdx.x << 6;
  int tid = threadIdx.x;
  #pragma unroll
  for (int it = 0; it < 16; ++it) {
    int idx = it * 256 + tid; int i = idx >> 6, tt = idx & 63;
    tile[tt][i] = (f16)u[((long)b * 64 + i) * 1024 + t0 + tt];
  }
  __syncthreads();
  #pragma unroll
  for (int it = 0; it < 16; ++it) {
    int idx = it * 256 + tid; int tt = idx >> 6, i = idx & 63;
    up[((long)(t0 + tt) * 32 + b) * 64 + i] = tile[tt][i];
  }
}

// Pack Wbig = [[A1 A2],[M1 M2]] (1024x1024 f16) into per-thread register layout.
__global__ void k_packw(const f16* __restrict__ A1, const f16* __restrict__ A2,
                        const f16* __restrict__ M1, const f16* __restrict__ M2,
                        unsigned int* __restrict__ Wp) {
  int U = blockIdx.x * 256 + threadIdx.x;   // 524288
  int p = U & 3; int V = U >> 2;
  int tid = V & 511; int sj = V >> 9;
  int jj = sj & 31; int s = sj >> 5;
  int q = tid & 3, r = tid >> 2;
  int R = s * 128 + r;
  int k = q * 256 + jj * 8 + p * 2;
  f16 g0, g1;
  if (R < 512) {
    if (k < 512) { g0 = A1[R * 512 + k];         g1 = A1[R * 512 + k + 1]; }
    else         { g0 = A2[R * 512 + k - 512];   g1 = A2[R * 512 + k - 511]; }
  } else {
    int Rm = R - 512;
    if (k < 512) { g0 = M1[Rm * 512 + k];        g1 = M1[Rm * 512 + k + 1]; }
    else         { g0 = M2[Rm * 512 + k - 512];  g1 = M2[Rm * 512 + k - 511]; }
  }
  unsigned int lo = __builtin_bit_cast(unsigned short, g0);
  unsigned int hi = __builtin_bit_cast(unsigned short, g1);
  Wp[U] = lo | (hi << 16);
}

// ============ the sequential scan: persistent, 256 WGs = 32 batches x 8 slices ============
// Sync: per-(t,b) line-padded store-only flags (no RMW, no fences in the loop).
// All cross-WG locations (flags, state) use agent-scope atomics (coherent at L3).
// Producer: __syncthreads (per-wave vmcnt(0) drain => state stores ack'd at coherence
// point) -> relaxed flag store. Consumer: relaxed poll (lanes 0-7, coalesced) ->
// compile-time memory barrier -> state load (control-dependent, coherent).
__global__ __launch_bounds__(512, 1) void k_scan(
    const uint4* __restrict__ Wp4,
    const f16* __restrict__ bHV,
    const float* __restrict__ b0,
    f16* __restrict__ Sst,
    unsigned int* __restrict__ flg)
{
  const int wg = blockIdx.x;
  const int s = wg >> 5, b = wg & 31;
  const int tid = threadIdx.x;
  const int q = tid & 3, r = tid >> 2;     // 4-way K-split, 128 rows/slice
  const int R = (s << 7) + r;
  const int lane = tid & 63;
  __shared__ __align__(16) unsigned int lds[4 * 132];

  // weights: 128 VGPRs/thread. The empty-asm "+v" keep-alives pin them: the loads
  // cannot be sunk/rematerialized into the t-loop (round-3 failure: VGPR_Count=84,
  // compiler re-read 256KB/WG/step through fence-invalidated L2 => L3-BW-bound).
  uint4 wreg[32];
  #pragma unroll
  for (int j = 0; j < 32; ++j) wreg[j] = Wp4[(long)(s * 32 + j) * 512 + tid];
  #pragma unroll
  for (int j = 0; j < 32; ++j)
    asm volatile("" : "+v"(wreg[j].x), "+v"(wreg[j].y), "+v"(wreg[j].z), "+v"(wreg[j].w));

  const float b0r = b0[R];
  const bool isV = (s >= 4);
  unsigned int* SstU = (unsigned int*)Sst;
  const unsigned int* lp = lds + q * 132;

  for (int t = 1; t < 1024; ++t) {
    // bias prefetch (independent, completes during poll)
    float bsv = (float)bHV[((long)(t - 1) * 32 + b) * 1024 + R];

    if (t > 1) {
      const unsigned int* fp = flg + ((long)(t - 1) * 32 + b) * 32;
      for (;;) {
        unsigned int v = 1u;
        if (lane < 8)
          v = __hip_atomic_load(fp + lane, __ATOMIC_RELAXED, __HIP_MEMORY_SCOPE_AGENT);
        if (__all(v != 0u)) break;
        __builtin_amdgcn_s_sleep(1);
      }
      asm volatile("" ::: "memory");   // compile-time only: no reordering across the poll
    }
    // cooperative coherent load of prev state row (512 dwords = 1024 f16)
    unsigned int sv = __hip_atomic_load(&SstU[((long)(t - 1) * 32 + b) * 512 + tid],
                                        __ATOMIC_RELAXED, __HIP_MEMORY_SCOPE_AGENT);
    lds[(tid >> 7) * 132 + (tid & 127)] = sv;
    __syncthreads();

    float acc = 0.0f;
    #pragma unroll
    for (int jj = 0; jj < 32; ++jj) {
      uint4 s4 = *(const uint4*)(lp + jj * 4);
      acc = fdot2u(s4.x, wreg[jj].x, acc);
      acc = fdot2u(s4.y, wreg[jj].y, acc);
      acc = fdot2u(s4.z, wreg[jj].z, acc);
      acc = fdot2u(s4.w, wreg[jj].w, acc);
    }
    acc += __shfl_xor(acc, 1, 64);
    acc += __shfl_xor(acc, 2, 64);

    float val = acc + bsv + b0r;
    if (isV) val = fmaxf(val, 0.0f);
    f16 hv = (f16)val;
    unsigned int hb = (unsigned int)__builtin_bit_cast(unsigned short, hv);
    unsigned int nb = __shfl_down(hb, 4, 64);   // row r+1's value
    if ((tid & 7) == 0) {
      __hip_atomic_store(&SstU[((long)t * 32 + b) * 512 + (R >> 1)], hb | (nb << 16),
                         __ATOMIC_RELAXED, __HIP_MEMORY_SCOPE_AGENT);
    }
    __syncthreads();   // per-wave vmcnt(0) drain before barrier => slice globally visible
    if (tid == 0)
      __hip_atomic_store(flg + ((long)t * 32 + b) * 32 + s, 1u,
                         __ATOMIC_RELAXED, __HIP_MEMORY_SCOPE_AGENT);
  }
}

// C32 [b][t][j] f32 -> out [b][j][t]
__global__ void k_trout(const float* __restrict__ C, float* __restrict__ out) {
  __shared__ float tile[64][65];
  int b = blockIdx.y, t0 = blockIdx.x << 6;
  int tid = threadIdx.x;
  #pragma unroll
  for (int it = 0; it < 16; ++it) {
    int idx = it * 256 + tid; int tt = idx >> 6, j = idx & 63;
    tile[j][tt] = C[((long)b * 1024 + t0 + tt) * 64 + j];
  }
  __syncthreads();
  #pragma unroll
  for (int it = 0; it < 16; ++it) {
    int idx = it * 256 + tid; int j = idx >> 6, tt = idx & 63;
    out[((long)b * 64 + j) * 1024 + t0 + tt] = tile[j][tt];
  }
}

// ============ host ============
extern "C" void kernel_launch(void* const* d_in, const int* in_sizes, int n_in,
                              void* d_out, int out_size, void* d_ws, size_t ws_size,
                              hipStream_t stream) {
  (void)in_sizes; (void)n_in; (void)out_size; (void)ws_size;
  const float* u   = (const float*)d_in[0];
  const float* E   = (const float*)d_in[1];
  const float* Fw  = (const float*)d_in[2];
  const float* Fb  = (const float*)d_in[3];
  const float* B1w = (const float*)d_in[4];
  const float* B2w = (const float*)d_in[5];
  const float* C2t = (const float*)d_in[6];
  const float* bv  = (const float*)d_in[7];
  const float* Dt  = (const float*)d_in[8];
  const float* C1w = (const float*)d_in[9];
  const float* D11 = (const float*)d_in[10];
  const float* D12 = (const float*)d_in[11];
  const float* by  = (const float*)d_in[12];
  const float* mul = (const float*)d_in[13];
  float* out = (float*)d_out;

  char* w = (char*)d_ws;
  size_t off = 0;
  auto alloc = [&](size_t bytes) { size_t o = off; off += (bytes + 255) & ~(size_t)255; return o; };

  f16*  UP    = (f16*)(w + alloc(1025L * 32 * 64 * 2));  // u packed [t][b][nu], padded t=1024 row
  f16*  E16   = (f16*)(w + alloc(262144L * 2));
  f16*  F16   = (f16*)(w + alloc(262144L * 2));
  f16*  B116  = (f16*)(w + alloc(262144L * 2));
  f16*  B216  = (f16*)(w + alloc(32768L * 2));
  f16*  CV16  = (f16*)(w + alloc(262144L * 2));
  f16*  DVT   = (f16*)(w + alloc(32768L * 2));
  f16*  XA    = (f16*)(w + alloc(262144L * 2));
  f16*  XB    = (f16*)(w + alloc(262144L * 2));
  f16*  Z16   = (f16*)(w + alloc(262144L * 2));
  float* Y32  = (float*)(w + alloc(262144L * 4));
  f16*  A1    = (f16*)(w + alloc(262144L * 2));
  f16*  A2    = (f16*)(w + alloc(262144L * 2));
  f16*  A3    = (f16*)(w + alloc(32768L * 2));
  f16*  M1    = (f16*)(w + alloc(262144L * 2));
  f16*  M2    = (f16*)(w + alloc(262144L * 2));
  f16*  CVA3  = (f16*)(w + alloc(32768L * 2));
  f16*  A3T   = (f16*)(w + alloc(32768L * 2));
  f16*  CVA3T = (f16*)(w + alloc(32768L * 2));
  unsigned int* WPK = (unsigned int*)(w + alloc(524288L * 4));
  f16*  WOUT  = (f16*)(w + alloc(69632L * 2));           // 1088x64
  float* CB   = (float*)(w + alloc(512L * 4));
  float* B0   = (float*)(w + alloc(1024L * 4));
  f16*  BHV   = (f16*)(w + alloc(1024L * 32 * 1024 * 2));  // per-step input biases [t][b][1024]
  f16*  SST   = (f16*)(w + alloc(1024L * 32 * 1024 * 2));  // state history [t][b][1024]
  float* C32  = (float*)(w + alloc(2097152L * 4));         // y pre-transpose [b][t][64]
  // FLG aliases C32: flags used only during k_scan; C32 written only after k_scan.
  unsigned int* FLG = (unsigned int*)C32;                  // [t][b][32] line-padded, 4 MB

  // init (every call: ws is re-poisoned before each timed launch)
  (void)hipMemsetAsync(UP, 0, 1025L * 32 * 64 * 2, stream);
  (void)hipMemsetAsync(FLG, 0, 1024L * 32 * 32 * 4, stream);
  (void)hipMemsetAsync(SST, 0, 32L * 1024 * 2, stream);    // h0 = 0 (w0 overwritten below)

  k_packu<<<dim3(16, 32), 256, 0, stream>>>(u, UP);
  k_cvt<<<1024, 256, 0, stream>>>(E, E16, 262144);
  k_cvt<<<1024, 256, 0, stream>>>(Fw, F16, 262144);
  k_cvt<<<1024, 256, 0, stream>>>(B1w, B116, 262144);
  k_cvt<<<128, 256, 0, stream>>>(B2w, B216, 32768);
  k_build_cv<<<1024, 256, 0, stream>>>(C2t, mul, CV16);
  k_build_dvt<<<128, 256, 0, stream>>>(Dt, mul, DVT);

  // Newton: X <- X(2I - E X), X0 = 2I - E (4 iters, f16 storage, f32 accum)
  k_2im<<<1024, 256, 0, stream>>>(E, XA);
  f16 *X = XA, *Xo = XB;
  for (int it = 0; it < 4; ++it) {
    gemm16<0,0,0,0><<<dim3(8,8,1), 256, 0, stream>>>(E16, 512, 0, X, 512, Y32, 512, 0, nullptr, 512, 512, 512);
    k_2im<<<1024, 256, 0, stream>>>(Y32, Z16);
    gemm16<1,0,0,0><<<dim3(8,8,1), 256, 0, stream>>>(X, 512, 0, Z16, 512, Xo, 512, 0, nullptr, 512, 512, 512);
    f16* tmp = X; X = Xo; Xo = tmp;
  }

  // fused weights
  gemm16<1,0,0,0><<<dim3(8,8,1), 256, 0, stream>>>(X, 512, 0, F16, 512, A1, 512, 0, nullptr, 512, 512, 512);
  gemm16<1,0,0,0><<<dim3(8,8,1), 256, 0, stream>>>(X, 512, 0, B116, 512, A2, 512, 0, nullptr, 512, 512, 512);
  gemm16<1,0,0,0><<<dim3(8,1,1), 256, 0, stream>>>(X, 512, 0, B216, 64, A3, 64, 0, nullptr, 512, 64, 512);
  gemm16<1,0,0,0><<<dim3(8,8,1), 256, 0, stream>>>(CV16, 512, 0, A1, 512, M1, 512, 0, nullptr, 512, 512, 512);
  gemm16<1,0,0,0><<<dim3(8,8,1), 256, 0, stream>>>(CV16, 512, 0, A2, 512, M2, 512, 0, nullptr, 512, 512, 512);
  gemm16<1,0,0,0><<<dim3(8,1,1), 256, 0, stream>>>(CV16, 512, 0, A3, 64, CVA3, 64, 0, nullptr, 512, 64, 512);
  k_tr16<<<128, 256, 0, stream>>>(A3, A3T, 512, 64);
  k_tr16<<<128, 256, 0, stream>>>(CVA3, CVA3T, 512, 64);
  k_woutt<<<272, 256, 0, stream>>>(C1w, D11, D12, WOUT);
  k_cb<<<1, 512, 0, stream>>>(X, Fb, CB);
  k_bias0<<<2, 512, 0, stream>>>(CV16, CB, bv, B0);
  k_packw<<<2048, 256, 0, stream>>>(A1, A2, M1, M2, WPK);

  // per-step input biases: biasH[t] = u_t @ A3T ; biasV[t] = u_t @ CvA3T + u_{t+1} @ DvT
  gemm16<1,0,0,0><<<dim3(512,8,1), 256, 0, stream>>>(UP, 64, 0, A3T, 512, BHV, 1024, 0, nullptr, 32768, 512, 64);
  gemm16<1,0,0,0><<<dim3(512,8,1), 256, 0, stream>>>(UP, 64, 0, CVA3T, 512, BHV + 512, 1024, 0, nullptr, 32768, 512, 64);
  gemm16<1,1,0,0><<<dim3(512,8,1), 256, 0, stream>>>(UP + 2048, 64, 0, DVT, 512, BHV + 512, 1024, 0, nullptr, 32768, 512, 64);
  // w0 = relu(u_0 @ DvT + bv) -> Sst[0][b][512:]
  gemm16<1,0,1,1><<<dim3(1,8,1), 256, 0, stream>>>(UP, 64, 0, DVT, 512, SST + 512, 1024, 0, bv, 32, 512, 64);

  // the sequential recurrence
  k_scan<<<256, 512, 0, stream>>>((const uint4*)WPK, BHV, B0, SST, FLG);

  // y = [h;w] @ WoutT[0:1024] + u @ WoutT[1024:1088] + by   (batched over b)
  gemm16<0,0,0,0><<<dim3(16,1,32), 256, 0, stream>>>(SST, 32768, 1024, WOUT, 64, C32, 64, 65536, nullptr, 1024, 64, 1024);
  gemm16<0,1,0,1><<<dim3(16,1,32), 256, 0, stream>>>(UP, 2048, 64, WOUT + 65536, 64, C32, 64, 65536, by, 1024, 64, 64);
  k_trout<<<dim3(16, 32), 256, 0, stream>>>(C32, out);
}